// Round 10
// baseline (177.580 us; speedup 1.0000x reference)
//
#include <hip/hip_runtime.h>
#include <stdint.h>

typedef __attribute__((ext_vector_type(8))) __bf16 bf16x8;
typedef __attribute__((ext_vector_type(4))) __bf16 bf16x4;
typedef __attribute__((ext_vector_type(4))) float f32x4;

#define MFMA16(a, b, c) __builtin_amdgcn_mfma_f32_16x16x32_bf16(a, b, c, 0, 0, 0)

// async 16B global->LDS: lds dest must be wave-uniform base; lane writes at base+lane*16
__device__ __forceinline__ void async_ld16(const __bf16* g, __bf16* lds_base) {
    __builtin_amdgcn_global_load_lds(
        (const __attribute__((address_space(1))) void*)g,
        (__attribute__((address_space(3))) void*)lds_base, 16, 0, 0);
}

// ---------------------------------------------------------------- fused prep
__global__ __launch_bounds__(256) void k_prep(
    const float* __restrict__ hs, const float* __restrict__ w1,
    const float* __restrict__ w2, __bf16* __restrict__ hsb,
    __bf16* __restrict__ w1t, __bf16* __restrict__ w2t) {
    __shared__ __bf16 tile[32][33];
    int bid = blockIdx.x, tid = threadIdx.x;
    if (bid < 4096) {
        int i = (bid * 256 + tid) * 4;
        float4 v = *(const float4*)(hs + i);
        bf16x4 o;
        o.x = (__bf16)v.x; o.y = (__bf16)v.y; o.z = (__bf16)v.z; o.w = (__bf16)v.w;
        *(bf16x4*)(hsb + i) = o;
        return;
    }
    const float* in; __bf16* out; int C, tb;
    if (bid < 7168) { in = w1; out = w1t; C = 3072; tb = bid - 4096; }
    else            { in = w2; out = w2t; C = 1024; tb = bid - 7168; }
    const int R = 1024;
    int ntc = C >> 5;
    int c0 = (tb % ntc) * 32, r0 = (tb / ntc) * 32;
    int tx = tid & 31, ty = tid >> 5;  // 32 x 8
#pragma unroll
    for (int i = 0; i < 4; i++)
        tile[ty + i * 8][tx] = (__bf16)in[(size_t)(r0 + ty + i * 8) * C + c0 + tx];
    __syncthreads();
#pragma unroll
    for (int i = 0; i < 4; i++)
        out[(size_t)(c0 + ty + i * 8) * R + r0 + tx] = tile[tx][ty + i * 8];
}

// ---------------------------------------------------------------- QKV GEMM
// BK=32 DOUBLE-BUFFERED, attn-style single barrier per iter: stage(k+1) is
// issued before compute(k); the end-of-iter barrier (vmcnt0 drain) lands the
// DMA under the 16 MFMAs instead of exposing ~900cy HBM latency per iter.
// Same K order as before (bitwise-identical accumulation). XCD chunking +
// transposed Q/K epilogue (d in regs) + V transposed store kept from R4/R8.
__global__ __launch_bounds__(256, 3) void k_gemm_qkv(
    const __bf16* __restrict__ A, const __bf16* __restrict__ Bt,
    const float* __restrict__ bias,
    __bf16* __restrict__ Qo, __bf16* __restrict__ Ko, __bf16* __restrict__ Vo) {
    __shared__ __bf16 As[2][128 * 32];
    __shared__ __bf16 Bs[2][128 * 32];
    const int Kd = 1024;
    int lid = blockIdx.x;
    int xcd = lid & 7, c = lid >> 3;                 // c in 0..95
    int mi = (xcd >> 1) * 8 + c / 12;                // m-tile 0..31
    int ni = (xcd & 1) * 12 + c % 12;                // n-tile 0..23
    int n0 = ni * 128, m0 = mi * 128;
    bool tr = (ni < 16);                             // Q/K: transposed product
    int tid = threadIdx.x;
    int wv = tid >> 6, lane = tid & 63;
    int wm = (wv >> 1) * 64, wn = (wv & 1) * 64;
    int quad = lane >> 4, l16 = lane & 15;
    int lrow = lane >> 2, lcol = (lane & 3) * 8;     // staging: 16 rows x 4 chunks
    int o0 = tr ? wn : wm, o1 = tr ? wm : wn;
    f32x4 acc[4][4] = {};

    // stage one BK=32 slab of A and B into buffer `buf`
    auto stage = [&](int buf, int k0) {
#pragma unroll
        for (int r = 0; r < 2; r++) {
            int row = r * 64 + wv * 16;  // wave-uniform
            async_ld16(&A[(size_t)(m0 + row + lrow) * Kd + k0 + lcol], &As[buf][row * 32]);
            async_ld16(&Bt[(size_t)(n0 + row + lrow) * Kd + k0 + lcol], &Bs[buf][row * 32]);
        }
    };

    stage(0, 0);
    __syncthreads();  // drain prologue DMA

    for (int kk = 0; kk < 32; kk++) {
        int cur = kk & 1;
        if (kk + 1 < 32) stage(cur ^ 1, (kk + 1) * 32);  // async; drained by end barrier
        const __bf16* p0 = tr ? Bs[cur] : As[cur];
        const __bf16* p1 = tr ? As[cur] : Bs[cur];
        bf16x8 f0[4], f1[4];
#pragma unroll
        for (int i = 0; i < 4; i++)
            f0[i] = *(const bf16x8*)(&p0[(o0 + i * 16 + l16) * 32 + quad * 8]);
#pragma unroll
        for (int j = 0; j < 4; j++)
            f1[j] = *(const bf16x8*)(&p1[(o1 + j * 16 + l16) * 32 + quad * 8]);
#pragma unroll
        for (int i = 0; i < 4; i++)
#pragma unroll
            for (int j = 0; j < 4; j++)
                acc[i][j] = MFMA16(f0[i], f1[j], acc[i][j]);
        __syncthreads();  // drains next-slab DMA; all reads of cur done
    }
    if (tr) {
#pragma unroll
        for (int i = 0; i < 4; i++) {
#pragma unroll
            for (int j = 0; j < 4; j++) {
                int nb = n0 + wn + i * 16 + quad * 4;
                int sec = nb >> 10, nl = nb & 1023;
                int h = nl >> 6, d = nl & 63;
                int sg = m0 + wm + j * 16 + l16;
                int bb = sg >> 11, s = sg & 2047;
                f32x4 bv = *(const f32x4*)(&bias[nb]);
                __bf16* dst = (sec == 0) ? Qo : Ko;
                // Q: fold 1/sqrt(64) * log2(e) (attention uses exp2)
                float scl = (sec == 0) ? 0.1803368801f : 1.0f;
                bf16x4 q4;
#pragma unroll
                for (int r = 0; r < 4; r++)
                    q4[r] = (__bf16)((acc[i][j][r] + bv[r]) * scl);
                *(bf16x4*)(&dst[((size_t)(bb * 16 + h) * 2048 + s) * 64 + d]) = q4;
            }
        }
    } else {
#pragma unroll
        for (int i = 0; i < 4; i++) {
#pragma unroll
            for (int j = 0; j < 4; j++) {
                int n = n0 + wn + j * 16 + l16;
                float bv = bias[n];
                int nl = n & 1023;
                int h = nl >> 6, d = nl & 63;
                int mbase = m0 + wm + i * 16 + quad * 4;
                int bb = mbase >> 11, s = mbase & 2047;
                bf16x4 v4;
#pragma unroll
                for (int r = 0; r < 4; r++) v4[r] = (__bf16)(acc[i][j][r] + bv);
                *(bf16x4*)(&Vo[((size_t)(bb * 16 + h) * 64 + d) * 2048 + s]) = v4;
            }
        }
    }
}

// ---------------------------------------------------------------- proj GEMM
__global__ __launch_bounds__(256, 3) void k_gemm_proj(
    const __bf16* __restrict__ A, const __bf16* __restrict__ Bt,
    const float* __restrict__ bias, float* __restrict__ out) {
    __shared__ __bf16 As[64 * 64];
    __shared__ __bf16 Bs[128 * 64];
    const int Kd = 1024;
    int lid = blockIdx.x;
    int xcd = lid & 7, c = lid >> 3;                 // c in 0..63
    int mi = xcd * 8 + (c >> 3);                     // m-tile 0..63
    int ni = c & 7;                                  // n-tile 0..7
    int n0 = ni * 128, m0 = mi * 64;
    int tid = threadIdx.x;
    int wv = tid >> 6, lane = tid & 63;
    int wm = (wv >> 1) * 32, wn = (wv & 1) * 64;
    int quad = lane >> 4, l16 = lane & 15;
    int rl = lane >> 3, sj = lane & 7;
    int sgo = (sj ^ rl) << 3;
    int swl = l16 & 7;
    f32x4 acc[4][2] = {};   // [n-frag][m-frag]
    for (int k0 = 0; k0 < Kd; k0 += 64) {
        __syncthreads();
#pragma unroll
        for (int r = 0; r < 2; r++) {
            int row = wv * 16 + r * 8;  // 64 A rows
            async_ld16(&A[(size_t)(m0 + row + rl) * Kd + k0 + sgo], &As[row * 64]);
        }
#pragma unroll
        for (int r = 0; r < 4; r++) {
            int row = wv * 32 + r * 8;  // 128 B rows
            async_ld16(&Bt[(size_t)(n0 + row + rl) * Kd + k0 + sgo], &Bs[row * 64]);
        }
        __syncthreads();
#pragma unroll
        for (int ks = 0; ks < 2; ks++) {
            bf16x8 f0[4], f1[2];
#pragma unroll
            for (int i = 0; i < 4; i++)
                f0[i] = *(const bf16x8*)(
                    &Bs[(wn + i * 16 + l16) * 64 + (((ks * 4 + quad) ^ swl) << 3)]);
#pragma unroll
            for (int j = 0; j < 2; j++)
                f1[j] = *(const bf16x8*)(
                    &As[(wm + j * 16 + l16) * 64 + (((ks * 4 + quad) ^ swl) << 3)]);
#pragma unroll
            for (int i = 0; i < 4; i++)
#pragma unroll
                for (int j = 0; j < 2; j++)
                    acc[i][j] = MFMA16(f0[i], f1[j], acc[i][j]);
        }
    }
#pragma unroll
    for (int i = 0; i < 4; i++) {
#pragma unroll
        for (int j = 0; j < 2; j++) {
            int nb = n0 + wn + i * 16 + quad * 4;
            int m = m0 + wm + j * 16 + l16;
            f32x4 bv = *(const f32x4*)(&bias[nb]);
            f32x4 o = acc[i][j] + bv;
            *(f32x4*)(&out[(size_t)m * 1024 + nb]) = o;
        }
    }
}

// ---------------------------------------------------------------- flash attention
// R8 proven version (43.2us): max-free associative softmax via exp2 (log2e
// folded into Q), 128q x 64k tiles, K/V double-buffered via global_load_lds,
// XOR chunk swizzle, Ps stride-72, l via ones-MFMA, fused normalize for
// single-chunk slots (t<=7), wave-uniform diagonal skip.
__device__ const int ATT_ORDER[24] = {7, 8, 10, 12, 14, 16, 18, 20, 22, 23, 6, 21,
                                      5, 19, 4, 17, 3, 15, 2, 13, 1, 11, 0, 9};

__global__ __launch_bounds__(256, 3) void k_attn(
    const __bf16* __restrict__ Qg, const __bf16* __restrict__ Kg,
    const __bf16* __restrict__ Vtg, __bf16* __restrict__ Op, float* __restrict__ Lp,
    __bf16* __restrict__ AOb) {
    __shared__ __bf16 Ksb[2][64 * 64];
    __shared__ __bf16 Vtb[2][64 * 64];
    __shared__ __bf16 Ps[128 * 72];
    int bh = blockIdx.x & 31;
    int slot = ATT_ORDER[blockIdx.x >> 5];
    int t, k0, k1;
    if (slot < 8) { t = slot; k0 = 0; k1 = 2 * t + 2; }
    else { int i2 = slot - 8; t = 8 + (i2 >> 1); k0 = (i2 & 1) * 16; k1 = min(k0 + 16, 2 * t + 2); }
    const __bf16* Qp = Qg + (size_t)bh * 2048 * 64;
    const __bf16* Kp = Kg + (size_t)bh * 2048 * 64;
    const __bf16* Vp = Vtg + (size_t)bh * 64 * 2048;
    int tid = threadIdx.x, wv = tid >> 6, lane = tid & 63;
    int quad = lane >> 4, l16 = lane & 15;
    int rl = lane >> 3, sj = lane & 7;        // staging: 8 rows x 8 chunks per call
    int sgo = (sj ^ rl) << 3;                 // swizzled global chunk offset (elems)
    int swl = l16 & 7;                        // fragment-read swizzle key

    // Q B-fragments: q-col = t*128 + wv*32 + qn*16 + l16 (loop-invariant)
    bf16x8 qf[2][2];
#pragma unroll
    for (int qn = 0; qn < 2; qn++)
#pragma unroll
        for (int ks = 0; ks < 2; ks++)
            qf[qn][ks] = *(const bf16x8*)(
                &Qp[(size_t)(t * 128 + wv * 32 + qn * 16 + l16) * 64 + ks * 32 + quad * 8]);
    const f32x4 zf = {0.f, 0.f, 0.f, 0.f};    // hoisted zero C operand
    const __bf16 one1 = (__bf16)1.0f;
    const bf16x8 onesv = {one1, one1, one1, one1, one1, one1, one1, one1};
    f32x4 acc_l[2] = {zf, zf};                // l via ones-MFMA (all rows equal)
    f32x4 acc_o[2][4] = {};
    int qwmax = t * 128 + wv * 32 + 31;       // max q this wave owns

    // async stage of one 64x64 K tile + V tile into buffer `buf`
    auto stage = [&](int buf, int kt) {
#pragma unroll
        for (int half = 0; half < 2; half++) {
            int r0 = wv * 16 + half * 8;  // wave-uniform, multiple of 8
            async_ld16(&Kp[(size_t)(kt * 64 + r0 + rl) * 64 + sgo], &Ksb[buf][r0 * 64]);
            async_ld16(&Vp[(size_t)(r0 + rl) * 2048 + kt * 64 + sgo], &Vtb[buf][r0 * 64]);
        }
    };

    stage(0, k0);
    __syncthreads();  // drain prologue loads

    for (int kt = k0; kt < k1; kt++) {
        int cur = (kt - k0) & 1;
        if (kt + 1 < k1) stage(cur ^ 1, kt + 1);  // async; drained by end barrier
        if (kt * 64 <= qwmax) {  // wave-uniform: skip fully-masked diagonal tiles
            const __bf16* Kc = Ksb[cur];
            const __bf16* Vc = Vtb[cur];
            // S^T: rows = 64 k (i*16+quad*4+r), cols = q (wv*32+qn*16+l16)
            f32x4 s[2][4];
#pragma unroll
            for (int ks = 0; ks < 2; ks++) {
                bf16x8 kf[4];
#pragma unroll
                for (int i = 0; i < 4; i++)
                    kf[i] = *(const bf16x8*)(
                        &Kc[(i * 16 + l16) * 64 + (((ks * 4 + quad) ^ swl) << 3)]);
                __builtin_amdgcn_s_setprio(1);
#pragma unroll
                for (int i = 0; i < 4; i++)
#pragma unroll
                    for (int qn = 0; qn < 2; qn++)
                        s[qn][i] = MFMA16(kf[i], qf[qn][ks], ks == 0 ? zf : s[qn][i]);
                __builtin_amdgcn_s_setprio(0);
            }
            // causal mask (elementwise only where the tile straddles the diagonal)
#pragma unroll
            for (int qn = 0; qn < 2; qn++) {
                int qmin = t * 128 + wv * 32 + qn * 16;
                if (kt * 64 + 63 > qmin) {
#pragma unroll
                    for (int i = 0; i < 4; i++)
#pragma unroll
                        for (int r = 0; r < 4; r++)
                            if (kt * 64 + i * 16 + quad * 4 + r > qmin + l16) s[qn][i][r] = -1e30f;
                }
            }
            // exp2 (no max subtraction) + P write (l comes from ones-MFMA)
#pragma unroll
            for (int qn = 0; qn < 2; qn++)
#pragma unroll
                for (int i = 0; i < 4; i++) {
                    bf16x4 pk;
#pragma unroll
                    for (int r = 0; r < 4; r++) pk[r] = (__bf16)exp2f(s[qn][i][r]);
                    *(bf16x4*)(&Ps[(wv * 32 + qn * 16 + l16) * 72 + i * 16 + quad * 4]) = pk;
                }
            // O^T += V^T P^T; l += 1^T P^T (P is wave-private band)
#pragma unroll
            for (int ks = 0; ks < 2; ks++) {
                bf16x8 pf[2];
#pragma unroll
                for (int qn = 0; qn < 2; qn++)
                    pf[qn] = *(const bf16x8*)(
                        &Ps[(wv * 32 + qn * 16 + l16) * 72 + ks * 32 + quad * 8]);
                bf16x8 vf[4];
#pragma unroll
                for (int i = 0; i < 4; i++)
                    vf[i] = *(const bf16x8*)(
                        &Vc[(i * 16 + l16) * 64 + (((ks * 4 + quad) ^ swl) << 3)]);
                __builtin_amdgcn_s_setprio(1);
#pragma unroll
                for (int i = 0; i < 4; i++)
#pragma unroll
                    for (int qn = 0; qn < 2; qn++)
                        acc_o[qn][i] = MFMA16(vf[i], pf[qn], acc_o[qn][i]);
#pragma unroll
                for (int qn = 0; qn < 2; qn++)
                    acc_l[qn] = MFMA16(onesv, pf[qn], acc_l[qn]);
                __builtin_amdgcn_s_setprio(0);
            }
        }
        __syncthreads();  // drains next-tile DMA; all reads of cur already done
    }
    // epilogue
    if (slot < 8) {
        // complete k-range: normalize and write AOb directly
        int b = bh >> 4, h = bh & 15;
#pragma unroll
        for (int qn = 0; qn < 2; qn++) {
            float inv = 1.f / acc_l[qn][0];
            int q = t * 128 + wv * 32 + qn * 16 + l16;
#pragma unroll
            for (int i = 0; i < 4; i++) {
                bf16x4 o4;
#pragma unroll
                for (int r = 0; r < 4; r++) o4[r] = (__bf16)(acc_o[qn][i][r] * inv);
                *(bf16x4*)(&AOb[((size_t)b * 2048 + q) * 1024 + h * 64 +
                                i * 16 + quad * 4]) = o4;
            }
        }
    } else {
        size_t pbase = (size_t)slot * 32 + bh;
#pragma unroll
        for (int qn = 0; qn < 2; qn++) {
            float ls = acc_l[qn][0];
            int ql = wv * 32 + qn * 16 + l16;
            if (quad == 0) Lp[pbase * 128 + ql] = ls;
#pragma unroll
            for (int i = 0; i < 4; i++) {
                bf16x4 o4;
#pragma unroll
                for (int r = 0; r < 4; r++) o4[r] = (__bf16)acc_o[qn][i][r];
                *(bf16x4*)(&Op[(pbase * 128 + ql) * 64 + i * 16 + quad * 4]) = o4;
            }
        }
    }
}

// Merge the 2 chunk partials per q-row for t>=8 only, normalize, write AOb.
__global__ __launch_bounds__(256) void k_attn_combine(
    const __bf16* __restrict__ Op, const float* __restrict__ Lp,
    __bf16* __restrict__ AOb) {
    int gid = blockIdx.x * 256 + threadIdx.x;  // 32*1024*16 threads
    int d4 = gid & 15;
    int q = 1024 + ((gid >> 4) & 1023);
    int bh = gid >> 14;
    int t = q >> 7, ql = q & 127;
    int base = 8 + 2 * (t - 8);
    float L = 0.f, o[4] = {};
#pragma unroll
    for (int c = 0; c < 2; c++) {
        size_t idx = (size_t)(base + c) * 32 + bh;
        L += Lp[idx * 128 + ql];
        bf16x4 p4 = *(const bf16x4*)(&Op[(idx * 128 + ql) * 64 + d4 * 4]);
#pragma unroll
        for (int r = 0; r < 4; r++) o[r] += (float)p4[r];
    }
    float inv = 1.f / L;
    int b = bh >> 4, h = bh & 15;
    bf16x4 o4;
#pragma unroll
    for (int r = 0; r < 4; r++) o4[r] = (__bf16)(o[r] * inv);
    *(bf16x4*)(&AOb[((size_t)b * 2048 + q) * 1024 + h * 64 + d4 * 4]) = o4;
}

// ---------------------------------------------------------------- launch
extern "C" void kernel_launch(void* const* d_in, const int* in_sizes, int n_in,
                              void* d_out, int out_size, void* d_ws, size_t ws_size,
                              hipStream_t stream) {
    const float* hs = (const float*)d_in[0];
    const float* w1 = (const float*)d_in[1];
    const float* b1 = (const float*)d_in[2];
    const float* w2 = (const float*)d_in[3];
    const float* b2 = (const float*)d_in[4];
    float* out = (float*)d_out;

    char* ws = (char*)d_ws;
    __bf16* hsb = (__bf16*)(ws);                               // [0,8M), dead after qkv
    __bf16* w1t = (__bf16*)(ws + (size_t)8 * 1024 * 1024);     // [8,14M), dead after qkv
    __bf16* w2t = (__bf16*)(ws + (size_t)14 * 1024 * 1024);    // [14,16M)
    __bf16* Qb  = (__bf16*)(ws + (size_t)16 * 1024 * 1024);    // [16,24M) [B,H,S,D]
    __bf16* Kb  = (__bf16*)(ws + (size_t)24 * 1024 * 1024);    // [24,32M) [B,H,S,D]
    __bf16* Vb  = (__bf16*)(ws + (size_t)32 * 1024 * 1024);    // [32,40M) [B,H,D,S]
    __bf16* AOb = (__bf16*)(ws + (size_t)40 * 1024 * 1024);    // [40,48M) [B,S,E]
    __bf16* Opart = (__bf16*)(ws);                             // [0,12.6M) overlays hsb/w1t
    float*  Lpart = (float*)(ws + (size_t)13 * 1024 * 1024);   // [13,13.4M)

    k_prep<<<8192, 256, 0, stream>>>(hs, w1, w2, hsb, w1t, w2t);
    k_gemm_qkv<<<768, 256, 0, stream>>>(hsb, w1t, b1, Qb, Kb, Vb);
    k_attn<<<768, 256, 0, stream>>>(Qb, Kb, Vb, Opart, Lpart, AOb);
    k_attn_combine<<<2048, 256, 0, stream>>>(Opart, Lpart, AOb);
    k_gemm_proj<<<512, 256, 0, stream>>>(AOb, w2t, b2, out);
}

// Round 11
// 171.670 us; speedup vs baseline: 1.0344x; 1.0344x over previous
//
#include <hip/hip_runtime.h>
#include <stdint.h>

typedef __attribute__((ext_vector_type(8))) __bf16 bf16x8;
typedef __attribute__((ext_vector_type(4))) __bf16 bf16x4;
typedef __attribute__((ext_vector_type(4))) float f32x4;

#define MFMA16(a, b, c) __builtin_amdgcn_mfma_f32_16x16x32_bf16(a, b, c, 0, 0, 0)

// async 16B global->LDS: lds dest must be wave-uniform base; lane writes at base+lane*16
__device__ __forceinline__ void async_ld16(const __bf16* g, __bf16* lds_base) {
    __builtin_amdgcn_global_load_lds(
        (const __attribute__((address_space(1))) void*)g,
        (__attribute__((address_space(3))) void*)lds_base, 16, 0, 0);
}

// ---------------------------------------------------------------- fused prep
__global__ __launch_bounds__(256) void k_prep(
    const float* __restrict__ hs, const float* __restrict__ w1,
    const float* __restrict__ w2, __bf16* __restrict__ hsb,
    __bf16* __restrict__ w1t, __bf16* __restrict__ w2t) {
    __shared__ __bf16 tile[32][33];
    int bid = blockIdx.x, tid = threadIdx.x;
    if (bid < 4096) {
        int i = (bid * 256 + tid) * 4;
        float4 v = *(const float4*)(hs + i);
        bf16x4 o;
        o.x = (__bf16)v.x; o.y = (__bf16)v.y; o.z = (__bf16)v.z; o.w = (__bf16)v.w;
        *(bf16x4*)(hsb + i) = o;
        return;
    }
    const float* in; __bf16* out; int C, tb;
    if (bid < 7168) { in = w1; out = w1t; C = 3072; tb = bid - 4096; }
    else            { in = w2; out = w2t; C = 1024; tb = bid - 7168; }
    const int R = 1024;
    int ntc = C >> 5;
    int c0 = (tb % ntc) * 32, r0 = (tb / ntc) * 32;
    int tx = tid & 31, ty = tid >> 5;  // 32 x 8
#pragma unroll
    for (int i = 0; i < 4; i++)
        tile[ty + i * 8][tx] = (__bf16)in[(size_t)(r0 + ty + i * 8) * C + c0 + tx];
    __syncthreads();
#pragma unroll
    for (int i = 0; i < 4; i++)
        out[(size_t)(c0 + ty + i * 8) * R + r0 + tx] = tile[tx][ty + i * 8];
}

// ---------------------------------------------------------------- QKV GEMM
// m97 structure, BK=64, XOR chunk swizzle on 128B rows. Q/K transposed product.
// Single-buffered: at 3 blocks/CU the cross-block wave overlap (m114) already
// hides staging latency; explicit dbuf measured neutral-to-negative (R10).
__global__ __launch_bounds__(256, 3) void k_gemm_qkv(
    const __bf16* __restrict__ A, const __bf16* __restrict__ Bt,
    const float* __restrict__ bias,
    __bf16* __restrict__ Qo, __bf16* __restrict__ Ko, __bf16* __restrict__ Vo) {
    __shared__ __bf16 As[128 * 64];
    __shared__ __bf16 Bs[128 * 64];
    const int Kd = 1024;
    int lid = blockIdx.x;
    int xcd = lid & 7, c = lid >> 3;                 // c in 0..95
    int mi = (xcd >> 1) * 8 + c / 12;                // m-tile 0..31
    int ni = (xcd & 1) * 12 + c % 12;                // n-tile 0..23
    int n0 = ni * 128, m0 = mi * 128;
    bool tr = (ni < 16);                             // Q/K: transposed product
    int tid = threadIdx.x;
    int wv = tid >> 6, lane = tid & 63;
    int wm = (wv >> 1) * 64, wn = (wv & 1) * 64;
    int quad = lane >> 4, l16 = lane & 15;
    int rl = lane >> 3, sj = lane & 7;               // staging 8 rows x 8 chunks
    int sgo = (sj ^ rl) << 3;                        // swizzled global chunk (elems)
    int swl = l16 & 7;                               // read-side swizzle key
    const __bf16* p0 = tr ? Bs : As;
    const __bf16* p1 = tr ? As : Bs;
    int o0 = tr ? wn : wm, o1 = tr ? wm : wn;
    f32x4 acc[4][4] = {};
    for (int k0 = 0; k0 < Kd; k0 += 64) {
        __syncthreads();
#pragma unroll
        for (int r = 0; r < 4; r++) {
            int row = wv * 32 + r * 8;  // wave-uniform, mult of 8
            async_ld16(&A[(size_t)(m0 + row + rl) * Kd + k0 + sgo], &As[row * 64]);
            async_ld16(&Bt[(size_t)(n0 + row + rl) * Kd + k0 + sgo], &Bs[row * 64]);
        }
        __syncthreads();
#pragma unroll
        for (int ks = 0; ks < 2; ks++) {
            bf16x8 f0[4], f1[4];
#pragma unroll
            for (int i = 0; i < 4; i++)
                f0[i] = *(const bf16x8*)(
                    &p0[(o0 + i * 16 + l16) * 64 + (((ks * 4 + quad) ^ swl) << 3)]);
#pragma unroll
            for (int j = 0; j < 4; j++)
                f1[j] = *(const bf16x8*)(
                    &p1[(o1 + j * 16 + l16) * 64 + (((ks * 4 + quad) ^ swl) << 3)]);
#pragma unroll
            for (int i = 0; i < 4; i++)
#pragma unroll
                for (int j = 0; j < 4; j++)
                    acc[i][j] = MFMA16(f0[i], f1[j], acc[i][j]);
        }
    }
    if (tr) {
#pragma unroll
        for (int i = 0; i < 4; i++) {
#pragma unroll
            for (int j = 0; j < 4; j++) {
                int nb = n0 + wn + i * 16 + quad * 4;
                int sec = nb >> 10, nl = nb & 1023;
                int h = nl >> 6, d = nl & 63;
                int sg = m0 + wm + j * 16 + l16;
                int bb = sg >> 11, s = sg & 2047;
                f32x4 bv = *(const f32x4*)(&bias[nb]);
                __bf16* dst = (sec == 0) ? Qo : Ko;
                // Q: fold 1/sqrt(64) * log2(e) (attention uses exp2)
                float scl = (sec == 0) ? 0.1803368801f : 1.0f;
                bf16x4 q4;
#pragma unroll
                for (int r = 0; r < 4; r++)
                    q4[r] = (__bf16)((acc[i][j][r] + bv[r]) * scl);
                *(bf16x4*)(&dst[((size_t)(bb * 16 + h) * 2048 + s) * 64 + d]) = q4;
            }
        }
    } else {
#pragma unroll
        for (int i = 0; i < 4; i++) {
#pragma unroll
            for (int j = 0; j < 4; j++) {
                int n = n0 + wn + j * 16 + l16;
                float bv = bias[n];
                int nl = n & 1023;
                int h = nl >> 6, d = nl & 63;
                int mbase = m0 + wm + i * 16 + quad * 4;
                int bb = mbase >> 11, s = mbase & 2047;
                bf16x4 v4;
#pragma unroll
                for (int r = 0; r < 4; r++) v4[r] = (__bf16)(acc[i][j][r] + bv);
                *(bf16x4*)(&Vo[((size_t)(bb * 16 + h) * 64 + d) * 2048 + s]) = v4;
            }
        }
    }
}

// ---------------------------------------------------------------- proj GEMM
__global__ __launch_bounds__(256, 3) void k_gemm_proj(
    const __bf16* __restrict__ A, const __bf16* __restrict__ Bt,
    const float* __restrict__ bias, float* __restrict__ out) {
    __shared__ __bf16 As[64 * 64];
    __shared__ __bf16 Bs[128 * 64];
    const int Kd = 1024;
    int lid = blockIdx.x;
    int xcd = lid & 7, c = lid >> 3;                 // c in 0..63
    int mi = xcd * 8 + (c >> 3);                     // m-tile 0..63
    int ni = c & 7;                                  // n-tile 0..7
    int n0 = ni * 128, m0 = mi * 64;
    int tid = threadIdx.x;
    int wv = tid >> 6, lane = tid & 63;
    int wm = (wv >> 1) * 32, wn = (wv & 1) * 64;
    int quad = lane >> 4, l16 = lane & 15;
    int rl = lane >> 3, sj = lane & 7;
    int sgo = (sj ^ rl) << 3;
    int swl = l16 & 7;
    f32x4 acc[4][2] = {};   // [n-frag][m-frag]
    for (int k0 = 0; k0 < Kd; k0 += 64) {
        __syncthreads();
#pragma unroll
        for (int r = 0; r < 2; r++) {
            int row = wv * 16 + r * 8;  // 64 A rows
            async_ld16(&A[(size_t)(m0 + row + rl) * Kd + k0 + sgo], &As[row * 64]);
        }
#pragma unroll
        for (int r = 0; r < 4; r++) {
            int row = wv * 32 + r * 8;  // 128 B rows
            async_ld16(&Bt[(size_t)(n0 + row + rl) * Kd + k0 + sgo], &Bs[row * 64]);
        }
        __syncthreads();
#pragma unroll
        for (int ks = 0; ks < 2; ks++) {
            bf16x8 f0[4], f1[2];
#pragma unroll
            for (int i = 0; i < 4; i++)
                f0[i] = *(const bf16x8*)(
                    &Bs[(wn + i * 16 + l16) * 64 + (((ks * 4 + quad) ^ swl) << 3)]);
#pragma unroll
            for (int j = 0; j < 2; j++)
                f1[j] = *(const bf16x8*)(
                    &As[(wm + j * 16 + l16) * 64 + (((ks * 4 + quad) ^ swl) << 3)]);
#pragma unroll
            for (int i = 0; i < 4; i++)
#pragma unroll
                for (int j = 0; j < 2; j++)
                    acc[i][j] = MFMA16(f0[i], f1[j], acc[i][j]);
        }
    }
#pragma unroll
    for (int i = 0; i < 4; i++) {
#pragma unroll
        for (int j = 0; j < 2; j++) {
            int nb = n0 + wn + i * 16 + quad * 4;
            int m = m0 + wm + j * 16 + l16;
            f32x4 bv = *(const f32x4*)(&bias[nb]);
            f32x4 o = acc[i][j] + bv;
            *(f32x4*)(&out[(size_t)m * 1024 + nb]) = o;
        }
    }
}

// ---------------------------------------------------------------- flash attention
// R8 proven version (43.2us): max-free associative softmax via exp2 (log2e
// folded into Q), 128q x 64k tiles, K/V double-buffered via global_load_lds,
// XOR chunk swizzle, Ps stride-72, l via ones-MFMA, fused normalize for
// single-chunk slots (t<=7), wave-uniform diagonal skip.
__device__ const int ATT_ORDER[24] = {7, 8, 10, 12, 14, 16, 18, 20, 22, 23, 6, 21,
                                      5, 19, 4, 17, 3, 15, 2, 13, 1, 11, 0, 9};

__global__ __launch_bounds__(256, 3) void k_attn(
    const __bf16* __restrict__ Qg, const __bf16* __restrict__ Kg,
    const __bf16* __restrict__ Vtg, __bf16* __restrict__ Op, float* __restrict__ Lp,
    __bf16* __restrict__ AOb) {
    __shared__ __bf16 Ksb[2][64 * 64];
    __shared__ __bf16 Vtb[2][64 * 64];
    __shared__ __bf16 Ps[128 * 72];
    int bh = blockIdx.x & 31;
    int slot = ATT_ORDER[blockIdx.x >> 5];
    int t, k0, k1;
    if (slot < 8) { t = slot; k0 = 0; k1 = 2 * t + 2; }
    else { int i2 = slot - 8; t = 8 + (i2 >> 1); k0 = (i2 & 1) * 16; k1 = min(k0 + 16, 2 * t + 2); }
    const __bf16* Qp = Qg + (size_t)bh * 2048 * 64;
    const __bf16* Kp = Kg + (size_t)bh * 2048 * 64;
    const __bf16* Vp = Vtg + (size_t)bh * 64 * 2048;
    int tid = threadIdx.x, wv = tid >> 6, lane = tid & 63;
    int quad = lane >> 4, l16 = lane & 15;
    int rl = lane >> 3, sj = lane & 7;        // staging: 8 rows x 8 chunks per call
    int sgo = (sj ^ rl) << 3;                 // swizzled global chunk offset (elems)
    int swl = l16 & 7;                        // fragment-read swizzle key

    // Q B-fragments: q-col = t*128 + wv*32 + qn*16 + l16 (loop-invariant)
    bf16x8 qf[2][2];
#pragma unroll
    for (int qn = 0; qn < 2; qn++)
#pragma unroll
        for (int ks = 0; ks < 2; ks++)
            qf[qn][ks] = *(const bf16x8*)(
                &Qp[(size_t)(t * 128 + wv * 32 + qn * 16 + l16) * 64 + ks * 32 + quad * 8]);
    const f32x4 zf = {0.f, 0.f, 0.f, 0.f};    // hoisted zero C operand
    const __bf16 one1 = (__bf16)1.0f;
    const bf16x8 onesv = {one1, one1, one1, one1, one1, one1, one1, one1};
    f32x4 acc_l[2] = {zf, zf};                // l via ones-MFMA (all rows equal)
    f32x4 acc_o[2][4] = {};
    int qwmax = t * 128 + wv * 32 + 31;       // max q this wave owns

    // async stage of one 64x64 K tile + V tile into buffer `buf`
    auto stage = [&](int buf, int kt) {
#pragma unroll
        for (int half = 0; half < 2; half++) {
            int r0 = wv * 16 + half * 8;  // wave-uniform, multiple of 8
            async_ld16(&Kp[(size_t)(kt * 64 + r0 + rl) * 64 + sgo], &Ksb[buf][r0 * 64]);
            async_ld16(&Vp[(size_t)(r0 + rl) * 2048 + kt * 64 + sgo], &Vtb[buf][r0 * 64]);
        }
    };

    stage(0, k0);
    __syncthreads();  // drain prologue loads

    for (int kt = k0; kt < k1; kt++) {
        int cur = (kt - k0) & 1;
        if (kt + 1 < k1) stage(cur ^ 1, kt + 1);  // async; drained by end barrier
        if (kt * 64 <= qwmax) {  // wave-uniform: skip fully-masked diagonal tiles
            const __bf16* Kc = Ksb[cur];
            const __bf16* Vc = Vtb[cur];
            // S^T: rows = 64 k (i*16+quad*4+r), cols = q (wv*32+qn*16+l16)
            f32x4 s[2][4];
#pragma unroll
            for (int ks = 0; ks < 2; ks++) {
                bf16x8 kf[4];
#pragma unroll
                for (int i = 0; i < 4; i++)
                    kf[i] = *(const bf16x8*)(
                        &Kc[(i * 16 + l16) * 64 + (((ks * 4 + quad) ^ swl) << 3)]);
                __builtin_amdgcn_s_setprio(1);
#pragma unroll
                for (int i = 0; i < 4; i++)
#pragma unroll
                    for (int qn = 0; qn < 2; qn++)
                        s[qn][i] = MFMA16(kf[i], qf[qn][ks], ks == 0 ? zf : s[qn][i]);
                __builtin_amdgcn_s_setprio(0);
            }
            // causal mask (elementwise only where the tile straddles the diagonal)
#pragma unroll
            for (int qn = 0; qn < 2; qn++) {
                int qmin = t * 128 + wv * 32 + qn * 16;
                if (kt * 64 + 63 > qmin) {
#pragma unroll
                    for (int i = 0; i < 4; i++)
#pragma unroll
                        for (int r = 0; r < 4; r++)
                            if (kt * 64 + i * 16 + quad * 4 + r > qmin + l16) s[qn][i][r] = -1e30f;
                }
            }
            // exp2 (no max subtraction) + P write (l comes from ones-MFMA)
#pragma unroll
            for (int qn = 0; qn < 2; qn++)
#pragma unroll
                for (int i = 0; i < 4; i++) {
                    bf16x4 pk;
#pragma unroll
                    for (int r = 0; r < 4; r++) pk[r] = (__bf16)exp2f(s[qn][i][r]);
                    *(bf16x4*)(&Ps[(wv * 32 + qn * 16 + l16) * 72 + i * 16 + quad * 4]) = pk;
                }
            // O^T += V^T P^T; l += 1^T P^T (P is wave-private band)
#pragma unroll
            for (int ks = 0; ks < 2; ks++) {
                bf16x8 pf[2];
#pragma unroll
                for (int qn = 0; qn < 2; qn++)
                    pf[qn] = *(const bf16x8*)(
                        &Ps[(wv * 32 + qn * 16 + l16) * 72 + ks * 32 + quad * 8]);
                bf16x8 vf[4];
#pragma unroll
                for (int i = 0; i < 4; i++)
                    vf[i] = *(const bf16x8*)(
                        &Vc[(i * 16 + l16) * 64 + (((ks * 4 + quad) ^ swl) << 3)]);
                __builtin_amdgcn_s_setprio(1);
#pragma unroll
                for (int i = 0; i < 4; i++)
#pragma unroll
                    for (int qn = 0; qn < 2; qn++)
                        acc_o[qn][i] = MFMA16(vf[i], pf[qn], acc_o[qn][i]);
#pragma unroll
                for (int qn = 0; qn < 2; qn++)
                    acc_l[qn] = MFMA16(onesv, pf[qn], acc_l[qn]);
                __builtin_amdgcn_s_setprio(0);
            }
        }
        __syncthreads();  // drains next-tile DMA; all reads of cur already done
    }
    // epilogue
    if (slot < 8) {
        // complete k-range: normalize and write AOb directly
        int b = bh >> 4, h = bh & 15;
#pragma unroll
        for (int qn = 0; qn < 2; qn++) {
            float inv = 1.f / acc_l[qn][0];
            int q = t * 128 + wv * 32 + qn * 16 + l16;
#pragma unroll
            for (int i = 0; i < 4; i++) {
                bf16x4 o4;
#pragma unroll
                for (int r = 0; r < 4; r++) o4[r] = (__bf16)(acc_o[qn][i][r] * inv);
                *(bf16x4*)(&AOb[((size_t)b * 2048 + q) * 1024 + h * 64 +
                                i * 16 + quad * 4]) = o4;
            }
        }
    } else {
        size_t pbase = (size_t)slot * 32 + bh;
#pragma unroll
        for (int qn = 0; qn < 2; qn++) {
            float ls = acc_l[qn][0];
            int ql = wv * 32 + qn * 16 + l16;
            if (quad == 0) Lp[pbase * 128 + ql] = ls;
#pragma unroll
            for (int i = 0; i < 4; i++) {
                bf16x4 o4;
#pragma unroll
                for (int r = 0; r < 4; r++) o4[r] = (__bf16)acc_o[qn][i][r];
                *(bf16x4*)(&Op[(pbase * 128 + ql) * 64 + i * 16 + quad * 4]) = o4;
            }
        }
    }
}

// Merge the 2 chunk partials per q-row for t>=8 only, normalize, write AOb.
__global__ __launch_bounds__(256) void k_attn_combine(
    const __bf16* __restrict__ Op, const float* __restrict__ Lp,
    __bf16* __restrict__ AOb) {
    int gid = blockIdx.x * 256 + threadIdx.x;  // 32*1024*16 threads
    int d4 = gid & 15;
    int q = 1024 + ((gid >> 4) & 1023);
    int bh = gid >> 14;
    int t = q >> 7, ql = q & 127;
    int base = 8 + 2 * (t - 8);
    float L = 0.f, o[4] = {};
#pragma unroll
    for (int c = 0; c < 2; c++) {
        size_t idx = (size_t)(base + c) * 32 + bh;
        L += Lp[idx * 128 + ql];
        bf16x4 p4 = *(const bf16x4*)(&Op[(idx * 128 + ql) * 64 + d4 * 4]);
#pragma unroll
        for (int r = 0; r < 4; r++) o[r] += (float)p4[r];
    }
    float inv = 1.f / L;
    int b = bh >> 4, h = bh & 15;
    bf16x4 o4;
#pragma unroll
    for (int r = 0; r < 4; r++) o4[r] = (__bf16)(o[r] * inv);
    *(bf16x4*)(&AOb[((size_t)b * 2048 + q) * 1024 + h * 64 + d4 * 4]) = o4;
}

// ---------------------------------------------------------------- launch
extern "C" void kernel_launch(void* const* d_in, const int* in_sizes, int n_in,
                              void* d_out, int out_size, void* d_ws, size_t ws_size,
                              hipStream_t stream) {
    const float* hs = (const float*)d_in[0];
    const float* w1 = (const float*)d_in[1];
    const float* b1 = (const float*)d_in[2];
    const float* w2 = (const float*)d_in[3];
    const float* b2 = (const float*)d_in[4];
    float* out = (float*)d_out;

    char* ws = (char*)d_ws;
    __bf16* hsb = (__bf16*)(ws);                               // [0,8M), dead after qkv
    __bf16* w1t = (__bf16*)(ws + (size_t)8 * 1024 * 1024);     // [8,14M), dead after qkv
    __bf16* w2t = (__bf16*)(ws + (size_t)14 * 1024 * 1024);    // [14,16M)
    __bf16* Qb  = (__bf16*)(ws + (size_t)16 * 1024 * 1024);    // [16,24M) [B,H,S,D]
    __bf16* Kb  = (__bf16*)(ws + (size_t)24 * 1024 * 1024);    // [24,32M) [B,H,S,D]
    __bf16* Vb  = (__bf16*)(ws + (size_t)32 * 1024 * 1024);    // [32,40M) [B,H,D,S]
    __bf16* AOb = (__bf16*)(ws + (size_t)40 * 1024 * 1024);    // [40,48M) [B,S,E]
    __bf16* Opart = (__bf16*)(ws);                             // [0,12.6M) overlays hsb/w1t
    float*  Lpart = (float*)(ws + (size_t)13 * 1024 * 1024);   // [13,13.4M)

    k_prep<<<8192, 256, 0, stream>>>(hs, w1, w2, hsb, w1t, w2t);
    k_gemm_qkv<<<768, 256, 0, stream>>>(hsb, w1t, b1, Qb, Kb, Vb);
    k_attn<<<768, 256, 0, stream>>>(Qb, Kb, Vb, Opart, Lpart, AOb);
    k_attn_combine<<<2048, 256, 0, stream>>>(Opart, Lpart, AOb);
    k_gemm_proj<<<512, 256, 0, stream>>>(AOb, w2t, b2, out);
}